// Round 20
// baseline (368.095 us; speedup 1.0000x reference)
//
#include <hip/hip_runtime.h>
#include <cstdint>
#include <cstddef>

// GRU (reset_after) + dense(1)+sigmoid, masked by per-batch length t.
// R20 = R19 (best: 364us; ping-pong pipeline, no x-prefetch regs) + ONE
// change: every weight VGPR is passed through an IDENTITY __shfl(w, j)
// (own-lane ds_bpermute). Bitwise identity, but non-rematerializable ->
// the register allocator is FORCED to keep all 132 weight VGPRs resident
// (R19's VGPR_Count=112 < the 132-reg weight set proved weights were
// being re-loaded from cache inside the step loop -- the last unmodeled
// stall). Live set ~245 VGPRs < 450 no-spill range at 1 wave/SIMD.
// Structure: ONE WAVE per sequence (512 x 64), ZERO barriers, lane j owns
// gate cols {j,64+j,128+j} full-K via v_dot2_f32_f16, h state f16 in LDS
// (same-wave write->read), z/r weights pre-negated, c weights pre-doubled.

typedef float  v2f __attribute__((ext_vector_type(2)));
typedef float  v4f __attribute__((ext_vector_type(4)));
typedef _Float16 h2 __attribute__((ext_vector_type(2)));
typedef _Float16 h8 __attribute__((ext_vector_type(8)));

__device__ __forceinline__ float frcp(float x) { return __builtin_amdgcn_rcpf(x); }

#if defined(__has_builtin)
#if __has_builtin(__builtin_amdgcn_fdot2)
#define HAVE_FDOT2 1
#endif
#endif

__device__ __forceinline__ float fdot2(h2 a, h2 b, float acc) {
#ifdef HAVE_FDOT2
    return __builtin_amdgcn_fdot2(a, b, acc, false);
#else
    return fmaf((float)a.x, (float)b.x, fmaf((float)a.y, (float)b.y, acc));
#endif
}

// Identity own-lane shuffle: bitwise no-op, but the result is a
// ds_bpermute output the compiler cannot rematerialize -> forces VGPR
// residency of weights (safe, unlike mass-tied empty inline asm: R8).
__device__ __forceinline__ h2 pinreg(h2 v, int lane) {
    int iv = __builtin_bit_cast(int, v);
    iv = __shfl(iv, lane, 64);
    return __builtin_bit_cast(h2, iv);
}

#define PAIR(v8, m) __builtin_shufflevector((v8), (v8), 2*(m), 2*(m)+1)

// 4 dot2s against one h8 vector, all pair indices literal
#define DOT4(acc, Warr, off, v)                              \
    acc = fdot2((Warr)[(off) + 0], PAIR((v), 0), acc);       \
    acc = fdot2((Warr)[(off) + 1], PAIR((v), 1), acc);       \
    acc = fdot2((Warr)[(off) + 2], PAIR((v), 2), acc);       \
    acc = fdot2((Warr)[(off) + 3], PAIR((v), 3), acc);

// One full GRU step on register set (HV, X0..X2); after the h-write it
// issues the NEXT step's LDS reads into (NHV, NX0..NX2) -- ping-pong, no
// copies. p-write goes after the reads (off the critical DS queue head).
#define GRU_STEP(C, HV, X0, X1, X2, NHV, NX0, NX1, NX2)                     \
  { float ran = brn;                                                        \
    DOT4(ran, Wr, 0, X0) DOT4(ran, Wr, 4, X1) DOT4(ran, Wr, 8, X2)          \
    float zan = bzn;                                                        \
    DOT4(zan, Wz, 0, X0) DOT4(zan, Wz, 4, X1) DOT4(zan, Wz, 8, X2)          \
    float xca = b0c2;                                                       \
    DOT4(xca, Wc, 0, X0) DOT4(xca, Wc, 4, X1) DOT4(xca, Wc, 8, X2)          \
    _Pragma("unroll")                                                       \
    for (int i = 0; i < 8; ++i) { DOT4(ran, Ur, 4 * i, HV[i]) }             \
    const float er = __expf(ran);                                           \
    _Pragma("unroll")                                                       \
    for (int i = 0; i < 8; ++i) { DOT4(zan, Uz, 4 * i, HV[i]) }             \
    const float ez = __expf(zan);                                           \
    float ca = b1c2;                                                        \
    _Pragma("unroll")                                                       \
    for (int i = 0; i < 8; ++i) { DOT4(ca, Uc, 4 * i, HV[i]) }              \
    const float r  = frcp(1.f + er);                                        \
    const float z  = frcp(1.f + ez);                                        \
    const float y  = fmaf(r, ca, xca);                                      \
    const float cg = 1.f - 2.f * frcp(1.f + __expf(y));                     \
    const float hn = fmaf(z, hold - cg, cg);                                \
    hold = hn;                                                              \
    h16[j] = (_Float16)hn;                                                  \
    { const h8* hp_ = (const h8*)h16;                                       \
      _Pragma("unroll")                                                     \
      for (int i = 0; i < 8; ++i) NHV[i] = hp_[i];                          \
      const h8* xp_ = (const h8*)(xbuf + (((C) + 1) & 63) * 24);            \
      NX0 = xp_[0]; NX1 = xp_[1]; NX2 = xp_[2]; }                           \
    p_lds[(C) * 66 + j] = hn * wdj;                                         \
  }

// stage 24 f32 (global row) -> 24 f16 (xbuf row j), no persistent regs
#define STAGE_ROW(BASEROW)                                                  \
  { const v4f* s_ = (const v4f*)(xsrc + (size_t)(BASEROW) * 24 + j * 24);   \
    const v4f g0_=s_[0],g1_=s_[1],g2_=s_[2],g3_=s_[3],g4_=s_[4],g5_=s_[5];  \
    h8 o0_, o1_, o2_;                                                       \
    _Pragma("unroll")                                                       \
    for (int i_ = 0; i_ < 4; ++i_) {                                        \
        o0_[i_]   = (_Float16)g0_[i_];  o0_[4+i_] = (_Float16)g1_[i_];      \
        o1_[i_]   = (_Float16)g2_[i_];  o1_[4+i_] = (_Float16)g3_[i_];      \
        o2_[i_]   = (_Float16)g4_[i_];  o2_[4+i_] = (_Float16)g5_[i_];      \
    }                                                                       \
    h8* d_ = (h8*)(xbuf + j * 24);                                          \
    d_[0] = o0_; d_[1] = o1_; d_[2] = o2_; }

__global__ __launch_bounds__(64, 1) void gru1_kernel(
    const float* __restrict__ xg,      // (512,1024,24)
    const int*   __restrict__ tg,      // (512,)
    const float* __restrict__ Wg,      // (24,192)
    const float* __restrict__ Ug,      // (64,192)
    const float* __restrict__ bg,      // (2,192)
    const float* __restrict__ Wdg,     // (64,1)
    const float* __restrict__ bdg,     // (1,)
    float*       __restrict__ outg)    // (512,1024)
{
    const int b = blockIdx.x;
    const int j = threadIdx.x;          // lane 0..63

    __shared__ __align__(16) _Float16 h16[64];          // f16 state, 128 B
    __shared__ __align__(16) _Float16 xbuf[64 * 24];    // chunk of x, f16
    __shared__ __align__(16) float    p_lds[64 * 66];   // [step][lane], pad 66
    __shared__ float o_last;

    const int   t    = tg[b];
    float*      outb = outg + (size_t)b * 1024;
    const float bdv  = bdg[0];

    if (t <= 0) {
        const float fill = frcp(1.f + __expf(-bdv));
        for (int i = j; i < 1024; i += 64) outb[i] = fill;
        return;
    }

    // ---- weight preload: f16 pairs along K; z/r negated, c doubled ----
    h2 Uz[32], Ur[32], Uc[32];
    #pragma unroll
    for (int k = 0; k < 32; ++k) {
        const float* r0 = Ug + (2 * k)     * 192;
        const float* r1 = Ug + (2 * k + 1) * 192;
        Uz[k] = (h2){ (_Float16)(-r0[j]),            (_Float16)(-r1[j]) };
        Ur[k] = (h2){ (_Float16)(-r0[64 + j]),       (_Float16)(-r1[64 + j]) };
        Uc[k] = (h2){ (_Float16)(2.f * r0[128 + j]), (_Float16)(2.f * r1[128 + j]) };
    }
    h2 Wz[12], Wr[12], Wc[12];
    #pragma unroll
    for (int d = 0; d < 12; ++d) {
        const float* r0 = Wg + (2 * d)     * 192;
        const float* r1 = Wg + (2 * d + 1) * 192;
        Wz[d] = (h2){ (_Float16)(-r0[j]),            (_Float16)(-r1[j]) };
        Wr[d] = (h2){ (_Float16)(-r0[64 + j]),       (_Float16)(-r1[64 + j]) };
        Wc[d] = (h2){ (_Float16)(2.f * r0[128 + j]), (_Float16)(2.f * r1[128 + j]) };
    }
    // ---- PIN: identity own-lane shuffle -> non-rematerializable ----
    #pragma unroll
    for (int k = 0; k < 32; ++k) {
        Uz[k] = pinreg(Uz[k], j);
        Ur[k] = pinreg(Ur[k], j);
        Uc[k] = pinreg(Uc[k], j);
    }
    #pragma unroll
    for (int d = 0; d < 12; ++d) {
        Wz[d] = pinreg(Wz[d], j);
        Wr[d] = pinreg(Wr[d], j);
        Wc[d] = pinreg(Wc[d], j);
    }

    const float bzn  = -(bg[j]      + bg[192 + j]);     // z: negated
    const float brn  = -(bg[64 + j] + bg[256 + j]);     // r: negated
    const float b0c2 = 2.f * bg[128 + j];               // c: doubled
    const float b1c2 = 2.f * bg[320 + j];
    const float wdj  = Wdg[j];

    const float* xsrc = xg + (size_t)b * 24576;   // 1024*24

    // ---- stage chunk 0; zero h; fill ping-pong set A ----
    STAGE_ROW(0);
    h16[j] = (_Float16)0.f;

    h8 hvA[8], hvB[8];
    h8 xaA, xbA, xcA, xaB, xbB, xcB;
    {
        const h8* hp = (const h8*)h16;
        #pragma unroll
        for (int i = 0; i < 8; ++i) hvA[i] = hp[i];
        const h8* xp = (const h8*)xbuf;
        xaA = xp[0]; xbA = xp[1]; xcA = xp[2];
    }

    float hold = 0.f;   // lane j's own h_j (f32, full precision)

    for (int base = 0; base < t; base += 64) {
        const int cnt = (t - base < 64) ? (t - base) : 64;

        if (base > 0) {
            // previous chunk done (64 steps, even -> active set is A).
            // Reduce previous outputs, commit this chunk's x (direct global
            // read), re-read x row 0 into A. hvA carries over.
            {
                const v2f* pr = (const v2f*)(p_lds + j * 66);
                v2f s2 = (v2f){0.f, 0.f};
                #pragma unroll
                for (int i = 0; i < 32; ++i) s2 += pr[i];
                outb[base - 64 + j] = frcp(1.f + __expf(-(s2.x + s2.y + bdv)));
            }
            STAGE_ROW(base);
            {
                const h8* xp = (const h8*)xbuf;
                xaA = xp[0]; xbA = xp[1]; xcA = xp[2];
            }
        }

        // ---- 2x-unrolled ping-pong steps (overrun by one harmless on the
        //      final odd chunk: p rows >= cnt never reduced, h unused) ----
        for (int c = 0; c < cnt; c += 2) {
            GRU_STEP(c,     hvA, xaA, xbA, xcA, hvB, xaB, xbB, xcB)
            GRU_STEP(c + 1, hvB, xaB, xbB, xcB, hvA, xaA, xbA, xcA)
        }
    }

    // ---- final (possibly partial) chunk reduce ----
    const int lastbase = ((t - 1) >> 6) << 6;
    const int lastcnt  = t - lastbase;
    if (j < lastcnt) {
        const v2f* pr = (const v2f*)(p_lds + j * 66);
        v2f s2 = (v2f){0.f, 0.f};
        #pragma unroll
        for (int i = 0; i < 32; ++i) s2 += pr[i];
        const float o = frcp(1.f + __expf(-(s2.x + s2.y + bdv)));
        outb[lastbase + j] = o;
        if (j == lastcnt - 1) o_last = o;
    }
    // ---- constant tail fill (same-wave visibility; R3-proven pattern) ----
    const float fill = o_last;
    for (int i = t + j; i < 1024; i += 64) outb[i] = fill;
}

extern "C" void kernel_launch(void* const* d_in, const int* in_sizes, int n_in,
                              void* d_out, int out_size, void* d_ws, size_t ws_size,
                              hipStream_t stream) {
    (void)in_sizes; (void)n_in; (void)d_ws; (void)ws_size; (void)out_size;
    const float* x  = (const float*)d_in[0];
    const int*   t  = (const int*)d_in[1];
    const float* W  = (const float*)d_in[2];
    const float* U  = (const float*)d_in[3];
    const float* bb = (const float*)d_in[4];
    const float* Wd = (const float*)d_in[5];
    const float* bd = (const float*)d_in[6];
    float* out = (float*)d_out;

    hipLaunchKernelGGL(gru1_kernel, dim3(512), dim3(64), 0, stream,
                       x, t, W, U, bb, Wd, bd, out);
}